// Round 4
// baseline (276.361 us; speedup 1.0000x reference)
//
#include <hip/hip_runtime.h>
#include <hip/hip_bf16.h>

// MaskedAttention R8b: identical to R8 (container infra flake, resubmit).
// R8 = R6 skeleton, vt precompute dropped (cost +14.6us feat vs ~5us attn),
// plus: (1) stride-72 Sp/Bt 8-way bank conflicts (3.48M) -> unpadded 128B rows
// + XOR swizzle byte^=(row&7)<<4 on write AND read; (2) LDS 27648->24576B ->
// 6 blk/CU, __launch_bounds__(256,6). Keep Bt+barrier (R7 lesson: shared
// staging amortizes latency across 4 waves; per-wave global V frags lost 2x).
// Prefetch after barrier into the same regs (all consumers pre-barrier).

#define B_ 16
#define L_ 576
#define H_ 12
#define D_ 64
#define M_ 8
#define NUM_STAB 1e-3f
#define RATIO 0.35355339059327373f  // 1/sqrt(M)

typedef __attribute__((ext_vector_type(8))) short short8;
typedef __attribute__((ext_vector_type(4))) float f32x4;

union Pack {
    uint4 u4;
    short8 s8;
    uint2 u2[2];
    unsigned u[4];
    unsigned short us[8];
};

__device__ inline unsigned short f2bf(float x) {  // RNE fp32 -> bf16 bits
    union { float f; unsigned u; } a; a.f = x;
    unsigned r = (a.u + 0x7FFFu + ((a.u >> 16) & 1u)) >> 16;
    return (unsigned short)r;
}
__device__ inline unsigned pk2(float lo, float hi) {  // v_cvt_pk_bf16_f32 (RNE)
    __hip_bfloat162 h = __float22bfloat162_rn(make_float2(lo, hi));
    union { __hip_bfloat162 b; unsigned u; } c; c.b = h;
    return c.u;
}
__device__ inline float bf2f(unsigned short u) {
    union { unsigned u; float f; } c; c.u = (unsigned)u << 16; return c.f;
}

// ws layout: cmask H*L f32 | w B*H*M f32 | qp bf16 | kp bf16
#define WS_W_OFF  (H_ * L_)
#define WS_QP_OFF (H_ * L_ + B_ * H_ * M_)
#define QP_ELEMS  ((size_t)B_ * H_ * L_ * M_)

// ---------------- kernel 1: features (bf16 out) + fused cmask col-sums ----------------
__global__ __launch_bounds__(256) void feat_kernel(const float* __restrict__ q,
                                                   const float* __restrict__ k,
                                                   const float* __restrict__ proj,
                                                   const float* __restrict__ mask,
                                                   unsigned short* __restrict__ qp,
                                                   unsigned short* __restrict__ kp,
                                                   float* __restrict__ cmask) {
    __shared__ float cred[4][16];
    const int lc = blockIdx.x, h = blockIdx.y, b = blockIdx.z, t = threadIdx.x;
    const int wv = t >> 6, l = t & 63, r8 = l >> 3, c8 = l & 7;
    const int row = lc * 32 + wv * 8 + r8;

    float4 pj0[8], pj1[8];
#pragma unroll
    for (int m = 0; m < 8; ++m) {
        pj0[m] = *(const float4*)(proj + m * 64 + c8 * 8);
        pj1[m] = *(const float4*)(proj + m * 64 + c8 * 8 + 4);
    }

#pragma unroll
    for (int s = 0; s < 2; ++s) {
        const float* src = s ? k : q;
        unsigned short* dst = s ? kp : qp;
        const float* xp = src + (((size_t)b * L_ + row) * H_ + h) * D_ + c8 * 8;
        float4 x0 = *(const float4*)xp;
        float4 x1 = *(const float4*)(xp + 4);
        x0.x *= RATIO; x0.y *= RATIO; x0.z *= RATIO; x0.w *= RATIO;
        x1.x *= RATIO; x1.y *= RATIO; x1.z *= RATIO; x1.w *= RATIO;
        float p[8];
#pragma unroll
        for (int m = 0; m < 8; ++m) {
            p[m] = x0.x * pj0[m].x + x0.y * pj0[m].y + x0.z * pj0[m].z + x0.w * pj0[m].w
                 + x1.x * pj1[m].x + x1.y * pj1[m].y + x1.z * pj1[m].z + x1.w * pj1[m].w;
        }
#pragma unroll
        for (int st = 1; st <= 4; st <<= 1) {
#pragma unroll
            for (int m = 0; m < 8; ++m) p[m] += __shfl_xor(p[m], st, 64);
        }
        float r = p[0];
        r = (c8 == 1) ? p[1] : r;
        r = (c8 == 2) ? p[2] : r;
        r = (c8 == 3) ? p[3] : r;
        r = (c8 == 4) ? p[4] : r;
        r = (c8 == 5) ? p[5] : r;
        r = (c8 == 6) ? p[6] : r;
        r = (c8 == 7) ? p[7] : r;
        r = fmaxf(r, 0.f) + NUM_STAB;
        dst[((size_t)(b * H_ + h) * L_ + row) * 8 + c8] = f2bf(r);
    }

    if (b < 2) {
        const int c = t & 15, rg = t >> 4;
        const int col0 = lc * 32 + b * 16;
        const float* mb = mask + (size_t)h * L_ * L_ + col0 + c;
        float a = 0.f;
#pragma unroll 4
        for (int k2 = 0; k2 < 36; ++k2) a += mb[(size_t)(rg + 16 * k2) * L_];
        a += __shfl_xor(a, 16, 64);
        a += __shfl_xor(a, 32, 64);
        if ((l >> 4) == 0) cred[wv][c] = a;
        __syncthreads();
        if (t < 16) cmask[h * L_ + col0 + t] = cred[0][t] + cred[1][t] + cred[2][t] + cred[3][t];
    }
}

// ---------------- kernel 2: w[b,h,m] = sum_j cmask[h,j] * k'[b,h,j,m] ----------------
__global__ __launch_bounds__(64) void wsum_kernel(const unsigned short* __restrict__ kp,
                                                  const float* __restrict__ cmask,
                                                  float* __restrict__ wbuf) {
    const int bh = blockIdx.x, lx = threadIdx.x;
    const int h = bh % H_;
    const unsigned short* kpb = kp + (size_t)bh * L_ * 8;
    const float* cm = cmask + h * L_;
    float a[8] = {0.f, 0.f, 0.f, 0.f, 0.f, 0.f, 0.f, 0.f};
    for (int j = lx; j < L_; j += 64) {
        const float c = cm[j];
        Pack pk; pk.u4 = *(const uint4*)(kpb + (size_t)j * 8);
#pragma unroll
        for (int m = 0; m < 8; ++m) a[m] += c * bf2f(pk.us[m]);
    }
#pragma unroll
    for (int st = 1; st < 64; st <<= 1) {
#pragma unroll
        for (int m = 0; m < 8; ++m) a[m] += __shfl_xor(a[m], st, 64);
    }
    float r = a[0];
    r = (lx == 1) ? a[1] : r;
    r = (lx == 2) ? a[2] : r;
    r = (lx == 3) ? a[3] : r;
    r = (lx == 4) ? a[4] : r;
    r = (lx == 5) ? a[5] : r;
    r = (lx == 6) ? a[6] : r;
    r = (lx == 7) ? a[7] : r;
    if (lx < 8) wbuf[(size_t)bh * 8 + lx] = r;
}

// ---------------- kernel 3: main attention ----------------
// grid 1728 (XCD-swizzled), block 256 (4 waves), 6 blocks/CU. 64i x 64d; 9 j-tiles.
// Per jt: phaseA (4 MFMA) -> V->bf16 Bt[slab] store (swizzled) + masked-S -> Sp
// (swizzled) -> barrier -> prefetch jt+1 (overlaps phase B) -> phase B (8 MFMA).
// XOR swizzle: unpadded 128B rows, phys = byte ^ ((row&7)<<4), applied on both
// write and read (same row -> same mask; row&7 == c15&7 for reads).
__global__ __launch_bounds__(256, 6) void attn_kernel(const float* __restrict__ v,
                                                      const float* __restrict__ mask,
                                                      const unsigned short* __restrict__ qp,
                                                      const unsigned short* __restrict__ kp,
                                                      const float* __restrict__ wbuf,
                                                      float* __restrict__ out) {
    __shared__ __align__(16) unsigned short Sp[4 * 16 * 64];  // 8192 B, wave-private, swizzled
    __shared__ __align__(16) unsigned short Bt[2][64 * 64];   // 16384 B, double-buffered, swizzled

    const int t = threadIdx.x;
    int id = blockIdx.x;
    const int bhi = id & 7; id >>= 3;
    const int blo = id & 1; id >>= 1;
    const int it = id % 9, h = id / 9;
    const int b = bhi * 2 + blo;
    const int i0 = it * 64;

    const int wv = t >> 6, l = t & 63, c15 = l & 15, kq = l >> 4;

    const float* maskbase = mask + (size_t)h * L_ * L_ + (size_t)(i0 + 16 * wv + c15) * L_ + 4 * kq;
    const unsigned short* kpb = kp + (size_t)(b * H_ + h) * L_ * 8;
    const float* vb = v + ((size_t)b * L_ * H_ + h) * D_ + l;

    char* SpB = (char*)Sp + wv * 2048;     // this wave's 16x64 bf16 chunk
    const int sxor = (c15 & 7) << 4;       // row-XOR mask for Sp and Bt reads (row&7 == c15&7)
    const int lxor = (l & 7) << 4;         // row-XOR mask for Bt writes (row = l = d)

    // loop-invariant Q' B-fragment (kq==0 lanes hold Q'[i0+16wv+c15][m0..7])
    short8 Bq;
    {
        Pack pk; pk.u4 = make_uint4(0, 0, 0, 0);
        if (kq == 0)
            pk.u4 = *(const uint4*)(qp + ((size_t)(b * H_ + h) * L_ + i0 + 16 * wv + c15) * 8);
        Bq = pk.s8;
    }

    f32x4 acc0 = {0.f, 0.f, 0.f, 0.f}, acc1 = acc0, acc2 = acc0, acc3 = acc0;
    const f32x4 zz = {0.f, 0.f, 0.f, 0.f};

    // ---- prologue prefetch for jt=0 ----
    float vf[16];
    float4 mv0, mv1, mv2, mv3;
    uint4 a0 = make_uint4(0, 0, 0, 0), a1 = a0, a2 = a0, a3 = a0;
    {
#pragma unroll
        for (int qv = 0; qv < 16; ++qv) vf[qv] = vb[(size_t)(16 * wv + qv) * (H_ * D_)];
        mv0 = *(const float4*)(maskbase + 0);
        mv1 = *(const float4*)(maskbase + 16);
        mv2 = *(const float4*)(maskbase + 32);
        mv3 = *(const float4*)(maskbase + 48);
        if (kq == 0) {
            a0 = *(const uint4*)(kpb + (size_t)(c15) * 8);
            a1 = *(const uint4*)(kpb + (size_t)(16 + c15) * 8);
            a2 = *(const uint4*)(kpb + (size_t)(32 + c15) * 8);
            a3 = *(const uint4*)(kpb + (size_t)(48 + c15) * 8);
        }
    }

    for (int jt = 0; jt < 9; ++jt) {
        const int slab = jt & 1;
        char* BtB = (char*)Bt[slab];

        // ---- phase A: S[j][i] for 64 j ----
        f32x4 s0, s1, s2, s3;
        {
            Pack p0, p1, p2, p3;
            p0.u4 = a0; p1.u4 = a1; p2.u4 = a2; p3.u4 = a3;
            __builtin_amdgcn_s_setprio(1);
            s0 = __builtin_amdgcn_mfma_f32_16x16x32_bf16(p0.s8, Bq, zz, 0, 0, 0);
            s1 = __builtin_amdgcn_mfma_f32_16x16x32_bf16(p1.s8, Bq, zz, 0, 0, 0);
            s2 = __builtin_amdgcn_mfma_f32_16x16x32_bf16(p2.s8, Bq, zz, 0, 0, 0);
            s3 = __builtin_amdgcn_mfma_f32_16x16x32_bf16(p3.s8, Bq, zz, 0, 0, 0);
            __builtin_amdgcn_s_setprio(0);
        }

        // ---- V -> Bt[slab], swizzled rows d=l, cols j=16wv+8q+e ----
        {
            Pack p0, p1;
#pragma unroll
            for (int qv = 0; qv < 4; ++qv) p0.u[qv] = pk2(vf[2 * qv], vf[2 * qv + 1]);
#pragma unroll
            for (int qv = 0; qv < 4; ++qv) p1.u[qv] = pk2(vf[8 + 2 * qv], vf[9 + 2 * qv]);
            const int base = l * 128 + 32 * wv;
            *(uint4*)(BtB + ((base) ^ lxor)) = p0.u4;
            *(uint4*)(BtB + ((base + 16) ^ lxor)) = p1.u4;
        }

        // ---- masked-S store (bf16) into swizzled wave-private Sp ----
        {
            const int sb = c15 * 128 + 8 * kq;
            uint2 st2;
            st2.x = pk2(s0[0] * mv0.x, s0[1] * mv0.y);
            st2.y = pk2(s0[2] * mv0.z, s0[3] * mv0.w);
            *(uint2*)(SpB + ((sb + 0) ^ sxor)) = st2;
            st2.x = pk2(s1[0] * mv1.x, s1[1] * mv1.y);
            st2.y = pk2(s1[2] * mv1.z, s1[3] * mv1.w);
            *(uint2*)(SpB + ((sb + 32) ^ sxor)) = st2;
            st2.x = pk2(s2[0] * mv2.x, s2[1] * mv2.y);
            st2.y = pk2(s2[2] * mv2.z, s2[3] * mv2.w);
            *(uint2*)(SpB + ((sb + 64) ^ sxor)) = st2;
            st2.x = pk2(s3[0] * mv3.x, s3[1] * mv3.y);
            st2.y = pk2(s3[2] * mv3.z, s3[3] * mv3.w);
            *(uint2*)(SpB + ((sb + 96) ^ sxor)) = st2;
        }

        __syncthreads();  // Bt[slab] + Sp ready; all globals already consumed

        // ---- prefetch jt+1 AFTER barrier (overlaps phase B; consumers all pre-barrier) ----
        {
            const int j0n = ((jt < 8) ? jt + 1 : 0) * 64;
#pragma unroll
            for (int qv = 0; qv < 16; ++qv) vf[qv] = vb[(size_t)(j0n + 16 * wv + qv) * (H_ * D_)];
            mv0 = *(const float4*)(maskbase + j0n + 0);
            mv1 = *(const float4*)(maskbase + j0n + 16);
            mv2 = *(const float4*)(maskbase + j0n + 32);
            mv3 = *(const float4*)(maskbase + j0n + 48);
            if (kq == 0) {
                a0 = *(const uint4*)(kpb + (size_t)(j0n + c15) * 8);
                a1 = *(const uint4*)(kpb + (size_t)(j0n + 16 + c15) * 8);
                a2 = *(const uint4*)(kpb + (size_t)(j0n + 32 + c15) * 8);
                a3 = *(const uint4*)(kpb + (size_t)(j0n + 48 + c15) * 8);
            }
        }

        // ---- phase B: O += S.V over K=64 (swizzled Sp/Bt reads) ----
        {
            short8 As0 = *(const short8*)(SpB + ((c15 * 128 + 16 * kq) ^ sxor));
            short8 As1 = *(const short8*)(SpB + ((c15 * 128 + 64 + 16 * kq) ^ sxor));
            __builtin_amdgcn_s_setprio(1);
#pragma unroll
            for (int di = 0; di < 4; ++di) {
                const int rb = (16 * di + c15) * 128;
                short8 B0 = *(const short8*)(BtB + ((rb + 16 * kq) ^ sxor));
                short8 B1 = *(const short8*)(BtB + ((rb + 64 + 16 * kq) ^ sxor));
                f32x4* ap = (di == 0) ? &acc0 : (di == 1) ? &acc1 : (di == 2) ? &acc2 : &acc3;
                *ap = __builtin_amdgcn_mfma_f32_16x16x32_bf16(As0, B0, *ap, 0, 0, 0);
                *ap = __builtin_amdgcn_mfma_f32_16x16x32_bf16(As1, B1, *ap, 0, 0, 0);
            }
            __builtin_amdgcn_s_setprio(0);
        }
    }

    // ---- epilogue: normalizer n_i = q'_i . w (exact reassociation) ----
    const float* wp = wbuf + (size_t)(b * H_ + h) * 8;
    const float4 w0 = *(const float4*)wp;
    const float4 w1 = *(const float4*)(wp + 4);
    Pack pq;
    pq.u4 = *(const uint4*)(qp + ((size_t)(b * H_ + h) * L_ + i0 + 16 * wv + c15) * 8);
    float n = bf2f(pq.us[0]) * w0.x + bf2f(pq.us[1]) * w0.y +
              bf2f(pq.us[2]) * w0.z + bf2f(pq.us[3]) * w0.w +
              bf2f(pq.us[4]) * w1.x + bf2f(pq.us[5]) * w1.y +
              bf2f(pq.us[6]) * w1.z + bf2f(pq.us[7]) * w1.w;
    float iv[4];
#pragma unroll
    for (int r = 0; r < 4; ++r) iv[r] = 1.0f / __shfl(n, 4 * kq + r, 64);

    float* ob = out + (((size_t)b * L_ + i0 + 16 * wv + 4 * kq) * H_ + h) * D_ + c15;
    const f32x4 aa[4] = {acc0, acc1, acc2, acc3};
#pragma unroll
    for (int di = 0; di < 4; ++di)
#pragma unroll
        for (int r = 0; r < 4; ++r)
            ob[(size_t)r * (H_ * D_) + 16 * di] = aa[di][r] * iv[r];
}

extern "C" void kernel_launch(void* const* d_in, const int* in_sizes, int n_in,
                              void* d_out, int out_size, void* d_ws, size_t ws_size,
                              hipStream_t stream) {
    const float* q    = (const float*)d_in[0];
    const float* k    = (const float*)d_in[1];
    const float* v    = (const float*)d_in[2];
    const float* proj = (const float*)d_in[3];
    const float* mask = (const float*)d_in[4];
    float* out = (float*)d_out;

    float* ws = (float*)d_ws;
    float* cmask = ws;
    float* wbuf  = ws + WS_W_OFF;
    unsigned short* qp_w = (unsigned short*)(ws + WS_QP_OFF);
    unsigned short* kp_w = qp_w + QP_ELEMS;

    feat_kernel<<<dim3(L_ / 32, H_, B_), 256, 0, stream>>>(q, k, proj, mask, qp_w, kp_w, cmask);
    wsum_kernel<<<B_ * H_, 64, 0, stream>>>(kp_w, cmask, wbuf);
    attn_kernel<<<1728, 256, 0, stream>>>(v, mask, qp_w, kp_w, wbuf, out);
}

// Round 5
// 189.381 us; speedup vs baseline: 1.4593x; 1.4593x over previous
//
#include <hip/hip_runtime.h>
#include <hip/hip_bf16.h>

// MaskedAttention R9: R8b with __launch_bounds__(256,4).
// R8b post-mortem: swizzle worked (conflicts 3.48M->995K) but (256,6) capped
// VGPRs at ~85 and the ~64-reg prefetch pipeline spilled to scratch:
// WRITE_SIZE +90MB (= 6 regs x 4B x 64 x 4 x 1728 x 9), FETCH +178MB,
// dur 54.5->148.8us. Lesson (3rd time): this pipeline needs its registers.
// (256,4) is a floor, not a cap - R5 compiled to 64 VGPRs under it; at <=85
// VGPRs occupancy is LDS-limited at 24576B -> 6 blocks/CU, same as R8b aimed
// for, without spills.

#define B_ 16
#define L_ 576
#define H_ 12
#define D_ 64
#define M_ 8
#define NUM_STAB 1e-3f
#define RATIO 0.35355339059327373f  // 1/sqrt(M)

typedef __attribute__((ext_vector_type(8))) short short8;
typedef __attribute__((ext_vector_type(4))) float f32x4;

union Pack {
    uint4 u4;
    short8 s8;
    uint2 u2[2];
    unsigned u[4];
    unsigned short us[8];
};

__device__ inline unsigned short f2bf(float x) {  // RNE fp32 -> bf16 bits
    union { float f; unsigned u; } a; a.f = x;
    unsigned r = (a.u + 0x7FFFu + ((a.u >> 16) & 1u)) >> 16;
    return (unsigned short)r;
}
__device__ inline unsigned pk2(float lo, float hi) {  // v_cvt_pk_bf16_f32 (RNE)
    __hip_bfloat162 h = __float22bfloat162_rn(make_float2(lo, hi));
    union { __hip_bfloat162 b; unsigned u; } c; c.b = h;
    return c.u;
}
__device__ inline float bf2f(unsigned short u) {
    union { unsigned u; float f; } c; c.u = (unsigned)u << 16; return c.f;
}

// ws layout: cmask H*L f32 | w B*H*M f32 | qp bf16 | kp bf16
#define WS_W_OFF  (H_ * L_)
#define WS_QP_OFF (H_ * L_ + B_ * H_ * M_)
#define QP_ELEMS  ((size_t)B_ * H_ * L_ * M_)

// ---------------- kernel 1: features (bf16 out) + fused cmask col-sums ----------------
__global__ __launch_bounds__(256) void feat_kernel(const float* __restrict__ q,
                                                   const float* __restrict__ k,
                                                   const float* __restrict__ proj,
                                                   const float* __restrict__ mask,
                                                   unsigned short* __restrict__ qp,
                                                   unsigned short* __restrict__ kp,
                                                   float* __restrict__ cmask) {
    __shared__ float cred[4][16];
    const int lc = blockIdx.x, h = blockIdx.y, b = blockIdx.z, t = threadIdx.x;
    const int wv = t >> 6, l = t & 63, r8 = l >> 3, c8 = l & 7;
    const int row = lc * 32 + wv * 8 + r8;

    float4 pj0[8], pj1[8];
#pragma unroll
    for (int m = 0; m < 8; ++m) {
        pj0[m] = *(const float4*)(proj + m * 64 + c8 * 8);
        pj1[m] = *(const float4*)(proj + m * 64 + c8 * 8 + 4);
    }

#pragma unroll
    for (int s = 0; s < 2; ++s) {
        const float* src = s ? k : q;
        unsigned short* dst = s ? kp : qp;
        const float* xp = src + (((size_t)b * L_ + row) * H_ + h) * D_ + c8 * 8;
        float4 x0 = *(const float4*)xp;
        float4 x1 = *(const float4*)(xp + 4);
        x0.x *= RATIO; x0.y *= RATIO; x0.z *= RATIO; x0.w *= RATIO;
        x1.x *= RATIO; x1.y *= RATIO; x1.z *= RATIO; x1.w *= RATIO;
        float p[8];
#pragma unroll
        for (int m = 0; m < 8; ++m) {
            p[m] = x0.x * pj0[m].x + x0.y * pj0[m].y + x0.z * pj0[m].z + x0.w * pj0[m].w
                 + x1.x * pj1[m].x + x1.y * pj1[m].y + x1.z * pj1[m].z + x1.w * pj1[m].w;
        }
#pragma unroll
        for (int st = 1; st <= 4; st <<= 1) {
#pragma unroll
            for (int m = 0; m < 8; ++m) p[m] += __shfl_xor(p[m], st, 64);
        }
        float r = p[0];
        r = (c8 == 1) ? p[1] : r;
        r = (c8 == 2) ? p[2] : r;
        r = (c8 == 3) ? p[3] : r;
        r = (c8 == 4) ? p[4] : r;
        r = (c8 == 5) ? p[5] : r;
        r = (c8 == 6) ? p[6] : r;
        r = (c8 == 7) ? p[7] : r;
        r = fmaxf(r, 0.f) + NUM_STAB;
        dst[((size_t)(b * H_ + h) * L_ + row) * 8 + c8] = f2bf(r);
    }

    if (b < 2) {
        const int c = t & 15, rg = t >> 4;
        const int col0 = lc * 32 + b * 16;
        const float* mb = mask + (size_t)h * L_ * L_ + col0 + c;
        float a = 0.f;
#pragma unroll 4
        for (int k2 = 0; k2 < 36; ++k2) a += mb[(size_t)(rg + 16 * k2) * L_];
        a += __shfl_xor(a, 16, 64);
        a += __shfl_xor(a, 32, 64);
        if ((l >> 4) == 0) cred[wv][c] = a;
        __syncthreads();
        if (t < 16) cmask[h * L_ + col0 + t] = cred[0][t] + cred[1][t] + cred[2][t] + cred[3][t];
    }
}

// ---------------- kernel 2: w[b,h,m] = sum_j cmask[h,j] * k'[b,h,j,m] ----------------
__global__ __launch_bounds__(64) void wsum_kernel(const unsigned short* __restrict__ kp,
                                                  const float* __restrict__ cmask,
                                                  float* __restrict__ wbuf) {
    const int bh = blockIdx.x, lx = threadIdx.x;
    const int h = bh % H_;
    const unsigned short* kpb = kp + (size_t)bh * L_ * 8;
    const float* cm = cmask + h * L_;
    float a[8] = {0.f, 0.f, 0.f, 0.f, 0.f, 0.f, 0.f, 0.f};
    for (int j = lx; j < L_; j += 64) {
        const float c = cm[j];
        Pack pk; pk.u4 = *(const uint4*)(kpb + (size_t)j * 8);
#pragma unroll
        for (int m = 0; m < 8; ++m) a[m] += c * bf2f(pk.us[m]);
    }
#pragma unroll
    for (int st = 1; st < 64; st <<= 1) {
#pragma unroll
        for (int m = 0; m < 8; ++m) a[m] += __shfl_xor(a[m], st, 64);
    }
    float r = a[0];
    r = (lx == 1) ? a[1] : r;
    r = (lx == 2) ? a[2] : r;
    r = (lx == 3) ? a[3] : r;
    r = (lx == 4) ? a[4] : r;
    r = (lx == 5) ? a[5] : r;
    r = (lx == 6) ? a[6] : r;
    r = (lx == 7) ? a[7] : r;
    if (lx < 8) wbuf[(size_t)bh * 8 + lx] = r;
}

// ---------------- kernel 3: main attention ----------------
// grid 1728 (XCD-swizzled), block 256 (4 waves). 64i x 64d; 9 j-tiles.
// Per jt: phaseA (4 MFMA) -> V->bf16 Bt[slab] store (swizzled) + masked-S -> Sp
// (swizzled) -> barrier -> prefetch jt+1 (overlaps phase B) -> phase B (8 MFMA).
// XOR swizzle: unpadded 128B rows, phys = byte ^ ((row&7)<<4), write AND read.
__global__ __launch_bounds__(256, 4) void attn_kernel(const float* __restrict__ v,
                                                      const float* __restrict__ mask,
                                                      const unsigned short* __restrict__ qp,
                                                      const unsigned short* __restrict__ kp,
                                                      const float* __restrict__ wbuf,
                                                      float* __restrict__ out) {
    __shared__ __align__(16) unsigned short Sp[4 * 16 * 64];  // 8192 B, wave-private, swizzled
    __shared__ __align__(16) unsigned short Bt[2][64 * 64];   // 16384 B, double-buffered, swizzled

    const int t = threadIdx.x;
    int id = blockIdx.x;
    const int bhi = id & 7; id >>= 3;
    const int blo = id & 1; id >>= 1;
    const int it = id % 9, h = id / 9;
    const int b = bhi * 2 + blo;
    const int i0 = it * 64;

    const int wv = t >> 6, l = t & 63, c15 = l & 15, kq = l >> 4;

    const float* maskbase = mask + (size_t)h * L_ * L_ + (size_t)(i0 + 16 * wv + c15) * L_ + 4 * kq;
    const unsigned short* kpb = kp + (size_t)(b * H_ + h) * L_ * 8;
    const float* vb = v + ((size_t)b * L_ * H_ + h) * D_ + l;

    char* SpB = (char*)Sp + wv * 2048;     // this wave's 16x64 bf16 chunk
    const int sxor = (c15 & 7) << 4;       // row-XOR mask for Sp and Bt reads (row&7 == c15&7)
    const int lxor = (l & 7) << 4;         // row-XOR mask for Bt writes (row = l = d)

    // loop-invariant Q' B-fragment (kq==0 lanes hold Q'[i0+16wv+c15][m0..7])
    short8 Bq;
    {
        Pack pk; pk.u4 = make_uint4(0, 0, 0, 0);
        if (kq == 0)
            pk.u4 = *(const uint4*)(qp + ((size_t)(b * H_ + h) * L_ + i0 + 16 * wv + c15) * 8);
        Bq = pk.s8;
    }

    f32x4 acc0 = {0.f, 0.f, 0.f, 0.f}, acc1 = acc0, acc2 = acc0, acc3 = acc0;
    const f32x4 zz = {0.f, 0.f, 0.f, 0.f};

    // ---- prologue prefetch for jt=0 ----
    float vf[16];
    float4 mv0, mv1, mv2, mv3;
    uint4 a0 = make_uint4(0, 0, 0, 0), a1 = a0, a2 = a0, a3 = a0;
    {
#pragma unroll
        for (int qv = 0; qv < 16; ++qv) vf[qv] = vb[(size_t)(16 * wv + qv) * (H_ * D_)];
        mv0 = *(const float4*)(maskbase + 0);
        mv1 = *(const float4*)(maskbase + 16);
        mv2 = *(const float4*)(maskbase + 32);
        mv3 = *(const float4*)(maskbase + 48);
        if (kq == 0) {
            a0 = *(const uint4*)(kpb + (size_t)(c15) * 8);
            a1 = *(const uint4*)(kpb + (size_t)(16 + c15) * 8);
            a2 = *(const uint4*)(kpb + (size_t)(32 + c15) * 8);
            a3 = *(const uint4*)(kpb + (size_t)(48 + c15) * 8);
        }
    }

    for (int jt = 0; jt < 9; ++jt) {
        const int slab = jt & 1;
        char* BtB = (char*)Bt[slab];

        // ---- phase A: S[j][i] for 64 j ----
        f32x4 s0, s1, s2, s3;
        {
            Pack p0, p1, p2, p3;
            p0.u4 = a0; p1.u4 = a1; p2.u4 = a2; p3.u4 = a3;
            __builtin_amdgcn_s_setprio(1);
            s0 = __builtin_amdgcn_mfma_f32_16x16x32_bf16(p0.s8, Bq, zz, 0, 0, 0);
            s1 = __builtin_amdgcn_mfma_f32_16x16x32_bf16(p1.s8, Bq, zz, 0, 0, 0);
            s2 = __builtin_amdgcn_mfma_f32_16x16x32_bf16(p2.s8, Bq, zz, 0, 0, 0);
            s3 = __builtin_amdgcn_mfma_f32_16x16x32_bf16(p3.s8, Bq, zz, 0, 0, 0);
            __builtin_amdgcn_s_setprio(0);
        }

        // ---- V -> Bt[slab], swizzled rows d=l, cols j=16wv+8q+e ----
        {
            Pack p0, p1;
#pragma unroll
            for (int qv = 0; qv < 4; ++qv) p0.u[qv] = pk2(vf[2 * qv], vf[2 * qv + 1]);
#pragma unroll
            for (int qv = 0; qv < 4; ++qv) p1.u[qv] = pk2(vf[8 + 2 * qv], vf[9 + 2 * qv]);
            const int base = l * 128 + 32 * wv;
            *(uint4*)(BtB + ((base) ^ lxor)) = p0.u4;
            *(uint4*)(BtB + ((base + 16) ^ lxor)) = p1.u4;
        }

        // ---- masked-S store (bf16) into swizzled wave-private Sp ----
        {
            const int sb = c15 * 128 + 8 * kq;
            uint2 st2;
            st2.x = pk2(s0[0] * mv0.x, s0[1] * mv0.y);
            st2.y = pk2(s0[2] * mv0.z, s0[3] * mv0.w);
            *(uint2*)(SpB + ((sb + 0) ^ sxor)) = st2;
            st2.x = pk2(s1[0] * mv1.x, s1[1] * mv1.y);
            st2.y = pk2(s1[2] * mv1.z, s1[3] * mv1.w);
            *(uint2*)(SpB + ((sb + 32) ^ sxor)) = st2;
            st2.x = pk2(s2[0] * mv2.x, s2[1] * mv2.y);
            st2.y = pk2(s2[2] * mv2.z, s2[3] * mv2.w);
            *(uint2*)(SpB + ((sb + 64) ^ sxor)) = st2;
            st2.x = pk2(s3[0] * mv3.x, s3[1] * mv3.y);
            st2.y = pk2(s3[2] * mv3.z, s3[3] * mv3.w);
            *(uint2*)(SpB + ((sb + 96) ^ sxor)) = st2;
        }

        __syncthreads();  // Bt[slab] + Sp ready; all globals already consumed

        // ---- prefetch jt+1 AFTER barrier (overlaps phase B; consumers all pre-barrier) ----
        {
            const int j0n = ((jt < 8) ? jt + 1 : 0) * 64;
#pragma unroll
            for (int qv = 0; qv < 16; ++qv) vf[qv] = vb[(size_t)(j0n + 16 * wv + qv) * (H_ * D_)];
            mv0 = *(const float4*)(maskbase + j0n + 0);
            mv1 = *(const float4*)(maskbase + j0n + 16);
            mv2 = *(const float4*)(maskbase + j0n + 32);
            mv3 = *(const float4*)(maskbase + j0n + 48);
            if (kq == 0) {
                a0 = *(const uint4*)(kpb + (size_t)(j0n + c15) * 8);
                a1 = *(const uint4*)(kpb + (size_t)(j0n + 16 + c15) * 8);
                a2 = *(const uint4*)(kpb + (size_t)(j0n + 32 + c15) * 8);
                a3 = *(const uint4*)(kpb + (size_t)(j0n + 48 + c15) * 8);
            }
        }

        // ---- phase B: O += S.V over K=64 (swizzled Sp/Bt reads) ----
        {
            short8 As0 = *(const short8*)(SpB + ((c15 * 128 + 16 * kq) ^ sxor));
            short8 As1 = *(const short8*)(SpB + ((c15 * 128 + 64 + 16 * kq) ^ sxor));
            __builtin_amdgcn_s_setprio(1);
#pragma unroll
            for (int di = 0; di < 4; ++di) {
                const int rb = (16 * di + c15) * 128;
                short8 B0 = *(const short8*)(BtB + ((rb + 16 * kq) ^ sxor));
                short8 B1 = *(const short8*)(BtB + ((rb + 64 + 16 * kq) ^ sxor));
                f32x4* ap = (di == 0) ? &acc0 : (di == 1) ? &acc1 : (di == 2) ? &acc2 : &acc3;
                *ap = __builtin_amdgcn_mfma_f32_16x16x32_bf16(As0, B0, *ap, 0, 0, 0);
                *ap = __builtin_amdgcn_mfma_f32_16x16x32_bf16(As1, B1, *ap, 0, 0, 0);
            }
            __builtin_amdgcn_s_setprio(0);
        }
    }

    // ---- epilogue: normalizer n_i = q'_i . w (exact reassociation) ----
    const float* wp = wbuf + (size_t)(b * H_ + h) * 8;
    const float4 w0 = *(const float4*)wp;
    const float4 w1 = *(const float4*)(wp + 4);
    Pack pq;
    pq.u4 = *(const uint4*)(qp + ((size_t)(b * H_ + h) * L_ + i0 + 16 * wv + c15) * 8);
    float n = bf2f(pq.us[0]) * w0.x + bf2f(pq.us[1]) * w0.y +
              bf2f(pq.us[2]) * w0.z + bf2f(pq.us[3]) * w0.w +
              bf2f(pq.us[4]) * w1.x + bf2f(pq.us[5]) * w1.y +
              bf2f(pq.us[6]) * w1.z + bf2f(pq.us[7]) * w1.w;
    float iv[4];
#pragma unroll
    for (int r = 0; r < 4; ++r) iv[r] = 1.0f / __shfl(n, 4 * kq + r, 64);

    float* ob = out + (((size_t)b * L_ + i0 + 16 * wv + 4 * kq) * H_ + h) * D_ + c15;
    const f32x4 aa[4] = {acc0, acc1, acc2, acc3};
#pragma unroll
    for (int di = 0; di < 4; ++di)
#pragma unroll
        for (int r = 0; r < 4; ++r)
            ob[(size_t)r * (H_ * D_) + 16 * di] = aa[di][r] * iv[r];
}

extern "C" void kernel_launch(void* const* d_in, const int* in_sizes, int n_in,
                              void* d_out, int out_size, void* d_ws, size_t ws_size,
                              hipStream_t stream) {
    const float* q    = (const float*)d_in[0];
    const float* k    = (const float*)d_in[1];
    const float* v    = (const float*)d_in[2];
    const float* proj = (const float*)d_in[3];
    const float* mask = (const float*)d_in[4];
    float* out = (float*)d_out;

    float* ws = (float*)d_ws;
    float* cmask = ws;
    float* wbuf  = ws + WS_W_OFF;
    unsigned short* qp_w = (unsigned short*)(ws + WS_QP_OFF);
    unsigned short* kp_w = qp_w + QP_ELEMS;

    feat_kernel<<<dim3(L_ / 32, H_, B_), 256, 0, stream>>>(q, k, proj, mask, qp_w, kp_w, cmask);
    wsum_kernel<<<B_ * H_, 64, 0, stream>>>(kp_w, cmask, wbuf);
    attn_kernel<<<1728, 256, 0, stream>>>(v, mask, qp_w, kp_w, wbuf, out);
}

// Round 6
// 188.094 us; speedup vs baseline: 1.4693x; 1.0068x over previous
//
#include <hip/hip_runtime.h>
#include <hip/hip_bf16.h>

// MaskedAttention R10: kill the vmcnt(0) barrier drain.
// 5-round finding: attn pinned at 55-61us with every pipe <25% busy. Shared
// Bt forces __syncthreads 9x/block, and HIP __syncthreads drains vmcnt(0) ->
// all "prefetched" loads are force-completed at every barrier (convoy on
// congested latency). Fix: re-decompose so wave wv owns d-slice [16wv,16wv+16)
// and holds its V fragment IN REGISTERS (wave-private loads, same coalescing,
// no Bt at all). Only Sp (VALU/MFMA-produced) crosses waves -> barrier becomes
// raw `s_waitcnt lgkmcnt(0); s_barrier` (global loads stay in flight across
// it). Sp double-buffered (race-free with 1 barrier/jt), XOR-swizzled
// (reads 2-way = free). setprio dropped (m190-negative, R9 suspect).
// Bit-exact dataflow vs R9.

#define B_ 16
#define L_ 576
#define H_ 12
#define D_ 64
#define M_ 8
#define NUM_STAB 1e-3f
#define RATIO 0.35355339059327373f  // 1/sqrt(M)

typedef __attribute__((ext_vector_type(8))) short short8;
typedef __attribute__((ext_vector_type(4))) float f32x4;

union Pack {
    uint4 u4;
    short8 s8;
    uint2 u2[2];
    unsigned u[4];
    unsigned short us[8];
};

__device__ inline unsigned short f2bf(float x) {  // RNE fp32 -> bf16 bits
    union { float f; unsigned u; } a; a.f = x;
    unsigned r = (a.u + 0x7FFFu + ((a.u >> 16) & 1u)) >> 16;
    return (unsigned short)r;
}
__device__ inline unsigned pk2(float lo, float hi) {  // v_cvt_pk_bf16_f32 (RNE)
    __hip_bfloat162 h = __float22bfloat162_rn(make_float2(lo, hi));
    union { __hip_bfloat162 b; unsigned u; } c; c.b = h;
    return c.u;
}
__device__ inline float bf2f(unsigned short u) {
    union { unsigned u; float f; } c; c.u = (unsigned)u << 16; return c.f;
}

// ws layout: cmask H*L f32 | w B*H*M f32 | qp bf16 | kp bf16
#define WS_W_OFF  (H_ * L_)
#define WS_QP_OFF (H_ * L_ + B_ * H_ * M_)
#define QP_ELEMS  ((size_t)B_ * H_ * L_ * M_)

// ---------------- kernel 1: features (bf16 out) + fused cmask col-sums ----------------
__global__ __launch_bounds__(256) void feat_kernel(const float* __restrict__ q,
                                                   const float* __restrict__ k,
                                                   const float* __restrict__ proj,
                                                   const float* __restrict__ mask,
                                                   unsigned short* __restrict__ qp,
                                                   unsigned short* __restrict__ kp,
                                                   float* __restrict__ cmask) {
    __shared__ float cred[4][16];
    const int lc = blockIdx.x, h = blockIdx.y, b = blockIdx.z, t = threadIdx.x;
    const int wv = t >> 6, l = t & 63, r8 = l >> 3, c8 = l & 7;
    const int row = lc * 32 + wv * 8 + r8;

    float4 pj0[8], pj1[8];
#pragma unroll
    for (int m = 0; m < 8; ++m) {
        pj0[m] = *(const float4*)(proj + m * 64 + c8 * 8);
        pj1[m] = *(const float4*)(proj + m * 64 + c8 * 8 + 4);
    }

#pragma unroll
    for (int s = 0; s < 2; ++s) {
        const float* src = s ? k : q;
        unsigned short* dst = s ? kp : qp;
        const float* xp = src + (((size_t)b * L_ + row) * H_ + h) * D_ + c8 * 8;
        float4 x0 = *(const float4*)xp;
        float4 x1 = *(const float4*)(xp + 4);
        x0.x *= RATIO; x0.y *= RATIO; x0.z *= RATIO; x0.w *= RATIO;
        x1.x *= RATIO; x1.y *= RATIO; x1.z *= RATIO; x1.w *= RATIO;
        float p[8];
#pragma unroll
        for (int m = 0; m < 8; ++m) {
            p[m] = x0.x * pj0[m].x + x0.y * pj0[m].y + x0.z * pj0[m].z + x0.w * pj0[m].w
                 + x1.x * pj1[m].x + x1.y * pj1[m].y + x1.z * pj1[m].z + x1.w * pj1[m].w;
        }
#pragma unroll
        for (int st = 1; st <= 4; st <<= 1) {
#pragma unroll
            for (int m = 0; m < 8; ++m) p[m] += __shfl_xor(p[m], st, 64);
        }
        float r = p[0];
        r = (c8 == 1) ? p[1] : r;
        r = (c8 == 2) ? p[2] : r;
        r = (c8 == 3) ? p[3] : r;
        r = (c8 == 4) ? p[4] : r;
        r = (c8 == 5) ? p[5] : r;
        r = (c8 == 6) ? p[6] : r;
        r = (c8 == 7) ? p[7] : r;
        r = fmaxf(r, 0.f) + NUM_STAB;
        dst[((size_t)(b * H_ + h) * L_ + row) * 8 + c8] = f2bf(r);
    }

    if (b < 2) {
        const int c = t & 15, rg = t >> 4;
        const int col0 = lc * 32 + b * 16;
        const float* mb = mask + (size_t)h * L_ * L_ + col0 + c;
        float a = 0.f;
#pragma unroll 4
        for (int k2 = 0; k2 < 36; ++k2) a += mb[(size_t)(rg + 16 * k2) * L_];
        a += __shfl_xor(a, 16, 64);
        a += __shfl_xor(a, 32, 64);
        if ((l >> 4) == 0) cred[wv][c] = a;
        __syncthreads();
        if (t < 16) cmask[h * L_ + col0 + t] = cred[0][t] + cred[1][t] + cred[2][t] + cred[3][t];
    }
}

// ---------------- kernel 2: w[b,h,m] = sum_j cmask[h,j] * k'[b,h,j,m] ----------------
__global__ __launch_bounds__(64) void wsum_kernel(const unsigned short* __restrict__ kp,
                                                  const float* __restrict__ cmask,
                                                  float* __restrict__ wbuf) {
    const int bh = blockIdx.x, lx = threadIdx.x;
    const int h = bh % H_;
    const unsigned short* kpb = kp + (size_t)bh * L_ * 8;
    const float* cm = cmask + h * L_;
    float a[8] = {0.f, 0.f, 0.f, 0.f, 0.f, 0.f, 0.f, 0.f};
    for (int j = lx; j < L_; j += 64) {
        const float c = cm[j];
        Pack pk; pk.u4 = *(const uint4*)(kpb + (size_t)j * 8);
#pragma unroll
        for (int m = 0; m < 8; ++m) a[m] += c * bf2f(pk.us[m]);
    }
#pragma unroll
    for (int st = 1; st < 64; st <<= 1) {
#pragma unroll
        for (int m = 0; m < 8; ++m) a[m] += __shfl_xor(a[m], st, 64);
    }
    float r = a[0];
    r = (lx == 1) ? a[1] : r;
    r = (lx == 2) ? a[2] : r;
    r = (lx == 3) ? a[3] : r;
    r = (lx == 4) ? a[4] : r;
    r = (lx == 5) ? a[5] : r;
    r = (lx == 6) ? a[6] : r;
    r = (lx == 7) ? a[7] : r;
    if (lx < 8) wbuf[(size_t)bh * 8 + lx] = r;
}

// ---------------- kernel 3: main attention (lgkm-only barrier, V in regs) ----------------
// grid 1728 (XCD-swizzled), block 256 (4 waves). Block: 64i x 64d, 9 j-tiles.
// Wave wv owns d-slice [16wv,16wv+16): V frags live in regs (wave-private
// loads). Sp (S-tile) is the ONLY cross-wave data: double-buffered slabs,
// one raw lgkmcnt-barrier per jt (global loads stay in flight across it).
// Per jt: phaseA (4 MFMA) -> masked-S -> Sp[slab] -> Bv pack -> BARRIER ->
// issue jt+1 loads (a,mv,vf) -> phaseB: iw=0..3 read Sp[slab][iw], 8 MFMA.
__global__ __launch_bounds__(256, 4) void attn_kernel(const float* __restrict__ v,
                                                      const float* __restrict__ mask,
                                                      const unsigned short* __restrict__ qp,
                                                      const unsigned short* __restrict__ kp,
                                                      const float* __restrict__ wbuf,
                                                      float* __restrict__ out) {
    __shared__ __align__(16) unsigned short Sp[2][4][16 * 64];  // 16384 B

    const int t = threadIdx.x;
    int id = blockIdx.x;
    const int bhi = id & 7; id >>= 3;
    const int blo = id & 1; id >>= 1;
    const int it = id % 9, h = id / 9;
    const int b = bhi * 2 + blo;
    const int i0 = it * 64;

    const int wv = t >> 6, l = t & 63, c15 = l & 15, kq = l >> 4;
    const int sxor = (c15 & 7) << 4;   // Sp row-XOR (row == c15 for write & read)

    const float* maskbase = mask + (size_t)h * L_ * L_ + (size_t)(i0 + 16 * wv + c15) * L_ + 4 * kq;
    const unsigned short* kpb = kp + (size_t)(b * H_ + h) * L_ * 8;
    // wave-private V base: lane (c15,kq) reads d = 16wv+c15, j varies
    const float* vbase = v + ((size_t)b * L_ * H_ + h) * D_ + 16 * wv + c15;

    // loop-invariant Q' B-fragment (kq==0 lanes hold Q'[i0+16wv+c15][m0..7])
    short8 Bq;
    {
        Pack pk; pk.u4 = make_uint4(0, 0, 0, 0);
        if (kq == 0)
            pk.u4 = *(const uint4*)(qp + ((size_t)(b * H_ + h) * L_ + i0 + 16 * wv + c15) * 8);
        Bq = pk.s8;
    }

    f32x4 acc0 = {0.f, 0.f, 0.f, 0.f}, acc1 = acc0, acc2 = acc0, acc3 = acc0;
    const f32x4 zz = {0.f, 0.f, 0.f, 0.f};

    // single-buffered prefetch state (consumed pre-barrier, re-issued post-barrier)
    uint4 a0 = make_uint4(0, 0, 0, 0), a1 = a0, a2 = a0, a3 = a0;
    float4 mv0, mv1, mv2, mv3;
    float vf0[8], vf1[8];   // V[j = kq*8+e][d]  and  V[j = 32+kq*8+e][d]

    // ---- prologue: issue jt=0 loads ----
    if (kq == 0) {
        a0 = *(const uint4*)(kpb + (size_t)(c15) * 8);
        a1 = *(const uint4*)(kpb + (size_t)(16 + c15) * 8);
        a2 = *(const uint4*)(kpb + (size_t)(32 + c15) * 8);
        a3 = *(const uint4*)(kpb + (size_t)(48 + c15) * 8);
    }
    mv0 = *(const float4*)(maskbase + 0);
    mv1 = *(const float4*)(maskbase + 16);
    mv2 = *(const float4*)(maskbase + 32);
    mv3 = *(const float4*)(maskbase + 48);
#pragma unroll
    for (int e = 0; e < 8; ++e) vf0[e] = vbase[(size_t)(kq * 8 + e) * (H_ * D_)];
#pragma unroll
    for (int e = 0; e < 8; ++e) vf1[e] = vbase[(size_t)(32 + kq * 8 + e) * (H_ * D_)];

    for (int jt = 0; jt < 9; ++jt) {
        const int slab = jt & 1;
        char* SpW = (char*)Sp[slab][wv];   // this wave's producer chunk

        // ---- phase A: S[j][i] for 64 j (C: row=j-within, col=i-within) ----
        f32x4 s0, s1, s2, s3;
        {
            Pack p0, p1, p2, p3;
            p0.u4 = a0; p1.u4 = a1; p2.u4 = a2; p3.u4 = a3;
            s0 = __builtin_amdgcn_mfma_f32_16x16x32_bf16(p0.s8, Bq, zz, 0, 0, 0);
            s1 = __builtin_amdgcn_mfma_f32_16x16x32_bf16(p1.s8, Bq, zz, 0, 0, 0);
            s2 = __builtin_amdgcn_mfma_f32_16x16x32_bf16(p2.s8, Bq, zz, 0, 0, 0);
            s3 = __builtin_amdgcn_mfma_f32_16x16x32_bf16(p3.s8, Bq, zz, 0, 0, 0);
        }

        // ---- masked-S store into Sp[slab][wv] (swizzled; j = 16T+4kq+e at byte 32T+8kq) ----
        {
            const int sb = c15 * 128 + 8 * kq;
            uint2 st2;
            st2.x = pk2(s0[0] * mv0.x, s0[1] * mv0.y);
            st2.y = pk2(s0[2] * mv0.z, s0[3] * mv0.w);
            *(uint2*)(SpW + ((sb + 0) ^ sxor)) = st2;
            st2.x = pk2(s1[0] * mv1.x, s1[1] * mv1.y);
            st2.y = pk2(s1[2] * mv1.z, s1[3] * mv1.w);
            *(uint2*)(SpW + ((sb + 32) ^ sxor)) = st2;
            st2.x = pk2(s2[0] * mv2.x, s2[1] * mv2.y);
            st2.y = pk2(s2[2] * mv2.z, s2[3] * mv2.w);
            *(uint2*)(SpW + ((sb + 64) ^ sxor)) = st2;
            st2.x = pk2(s3[0] * mv3.x, s3[1] * mv3.y);
            st2.y = pk2(s3[2] * mv3.z, s3[3] * mv3.w);
            *(uint2*)(SpW + ((sb + 96) ^ sxor)) = st2;
        }

        // ---- pack this jt's V fragment (B-operand, k=j) ----
        Pack bv0, bv1;
#pragma unroll
        for (int q4 = 0; q4 < 4; ++q4) bv0.u[q4] = pk2(vf0[2 * q4], vf0[2 * q4 + 1]);
#pragma unroll
        for (int q4 = 0; q4 < 4; ++q4) bv1.u[q4] = pk2(vf1[2 * q4], vf1[2 * q4 + 1]);

        // ---- barrier: LDS-only drain; global prefetches stay in flight ----
        asm volatile("s_waitcnt lgkmcnt(0)\n\ts_barrier" ::: "memory");

        // ---- issue jt+1 loads (wave-private; consumed next iter pre-barrier) ----
        {
            const int j0n = ((jt < 8) ? jt + 1 : 0) * 64;
            if (kq == 0) {
                a0 = *(const uint4*)(kpb + (size_t)(j0n + c15) * 8);
                a1 = *(const uint4*)(kpb + (size_t)(j0n + 16 + c15) * 8);
                a2 = *(const uint4*)(kpb + (size_t)(j0n + 32 + c15) * 8);
                a3 = *(const uint4*)(kpb + (size_t)(j0n + 48 + c15) * 8);
            }
            mv0 = *(const float4*)(maskbase + j0n + 0);
            mv1 = *(const float4*)(maskbase + j0n + 16);
            mv2 = *(const float4*)(maskbase + j0n + 32);
            mv3 = *(const float4*)(maskbase + j0n + 48);
#pragma unroll
            for (int e = 0; e < 8; ++e) vf0[e] = vbase[(size_t)(j0n + kq * 8 + e) * (H_ * D_)];
#pragma unroll
            for (int e = 0; e < 8; ++e) vf1[e] = vbase[(size_t)(j0n + 32 + kq * 8 + e) * (H_ * D_)];
        }

        // ---- phase B: O[i, d-slice] += S.V, reading all 4 producer chunks ----
        {
            const char* SpR = (const char*)Sp[slab][0];
            const int rb = c15 * 128;
#pragma unroll
            for (int iw = 0; iw < 4; ++iw) {
                const char* ch = SpR + iw * 2048;
                short8 As0 = *(const short8*)(ch + ((rb + 16 * kq) ^ sxor));
                short8 As1 = *(const short8*)(ch + ((rb + 64 + 16 * kq) ^ sxor));
                f32x4* ap = (iw == 0) ? &acc0 : (iw == 1) ? &acc1 : (iw == 2) ? &acc2 : &acc3;
                *ap = __builtin_amdgcn_mfma_f32_16x16x32_bf16(As0, bv0.s8, *ap, 0, 0, 0);
                *ap = __builtin_amdgcn_mfma_f32_16x16x32_bf16(As1, bv1.s8, *ap, 0, 0, 0);
            }
        }
    }

    // ---- epilogue: n_i = q'_i . w;  out[i, 16wv+c15] = acc/n ----
    const float* wp = wbuf + (size_t)(b * H_ + h) * 8;
    const float4 w0 = *(const float4*)wp;
    const float4 w1 = *(const float4*)(wp + 4);
    const f32x4 aa[4] = {acc0, acc1, acc2, acc3};
#pragma unroll
    for (int iw = 0; iw < 4; ++iw) {
        Pack pq;
        pq.u4 = *(const uint4*)(qp + ((size_t)(b * H_ + h) * L_ + i0 + 16 * iw + c15) * 8);
        float n = bf2f(pq.us[0]) * w0.x + bf2f(pq.us[1]) * w0.y +
                  bf2f(pq.us[2]) * w0.z + bf2f(pq.us[3]) * w0.w +
                  bf2f(pq.us[4]) * w1.x + bf2f(pq.us[5]) * w1.y +
                  bf2f(pq.us[6]) * w1.z + bf2f(pq.us[7]) * w1.w;
        float* ob = out + (((size_t)b * L_ + i0 + 16 * iw) * H_ + h) * D_ + 16 * wv + c15;
#pragma unroll
        for (int r = 0; r < 4; ++r) {
            float iv = 1.0f / __shfl(n, 4 * kq + r, 64);
            ob[(size_t)(4 * kq + r) * (H_ * D_)] = aa[iw][r] * iv;
        }
    }
}

extern "C" void kernel_launch(void* const* d_in, const int* in_sizes, int n_in,
                              void* d_out, int out_size, void* d_ws, size_t ws_size,
                              hipStream_t stream) {
    const float* q    = (const float*)d_in[0];
    const float* k    = (const float*)d_in[1];
    const float* v    = (const float*)d_in[2];
    const float* proj = (const float*)d_in[3];
    const float* mask = (const float*)d_in[4];
    float* out = (float*)d_out;

    float* ws = (float*)d_ws;
    float* cmask = ws;
    float* wbuf  = ws + WS_W_OFF;
    unsigned short* qp_w = (unsigned short*)(ws + WS_QP_OFF);
    unsigned short* kp_w = qp_w + QP_ELEMS;

    feat_kernel<<<dim3(L_ / 32, H_, B_), 256, 0, stream>>>(q, k, proj, mask, qp_w, kp_w, cmask);
    wsum_kernel<<<B_ * H_, 64, 0, stream>>>(kp_w, cmask, wbuf);
    attn_kernel<<<1728, 256, 0, stream>>>(v, mask, qp_w, kp_w, wbuf, out);
}